// Round 1
// baseline (148.389 us; speedup 1.0000x reference)
//
#include <hip/hip_runtime.h>
#include <math.h>

#define BATCH 512
#define NPTS  512

__global__ __launch_bounds__(NPTS) void normals_fused_kernel(
    const float* __restrict__ normals, float* __restrict__ out)
{
    __shared__ float sx[NPTS], sy[NPTS], sz[NPTS];
    const int b   = blockIdx.x;
    const int tid = threadIdx.x;
    const float* base = normals + (size_t)b * NPTS * 3;

    // Coalesced load of 1536 floats, AoS -> SoA in LDS (one-time cost).
    for (int k = tid; k < NPTS * 3; k += NPTS) {
        float v = base[k];
        int row = k / 3, c = k - row * 3;
        if (c == 0)      sx[row] = v;
        else if (c == 1) sy[row] = v;
        else             sz[row] = v;
    }
    __syncthreads();

    const int   i  = tid;
    const float xi = sx[i], yi = sy[i], zi = sz[i];

    // Row sum over all j (including diagonal; subtracted afterwards).
    float s = 0.f;
    #pragma unroll 8
    for (int j = 0; j < NPTS; ++j) {
        float d = fmaf(xi, sx[j], fmaf(yi, sy[j], zi * sz[j]));
        d = fminf(fmaxf(d, -1.f), 1.f);
        s += __expf(-acosf(d));
    }
    {   // remove the j == i contribution (reference masks the diagonal)
        float d = fmaf(xi, xi, fmaf(yi, yi, zi * zi));
        d = fminf(fmaxf(d, -1.f), 1.f);
        s -= __expf(-acosf(d));
    }

    // Per-thread weighted normal; global-max division skipped (cancels
    // under the final normalization — uniform positive scale).
    float ax = s * xi, ay = s * yi, az = s * zi;

    // Wave(64)-level shuffle reduction.
    for (int off = 32; off > 0; off >>= 1) {
        ax += __shfl_down(ax, off, 64);
        ay += __shfl_down(ay, off, 64);
        az += __shfl_down(az, off, 64);
    }

    __shared__ float rx[8], ry[8], rz[8];
    const int wave = tid >> 6, lane = tid & 63;
    if (lane == 0) { rx[wave] = ax; ry[wave] = ay; rz[wave] = az; }
    __syncthreads();

    if (tid == 0) {
        float nx = 0.f, ny = 0.f, nz = 0.f;
        #pragma unroll
        for (int w = 0; w < 8; ++w) { nx += rx[w]; ny += ry[w]; nz += rz[w]; }
        float len2 = fmaf(nx, nx, fmaf(ny, ny, nz * nz));
        float inv  = rsqrtf(fmaxf(len2, 1e-20f));
        out[b * 3 + 0] = nx * inv;
        out[b * 3 + 1] = ny * inv;
        out[b * 3 + 2] = nz * inv;
    }
}

extern "C" void kernel_launch(void* const* d_in, const int* in_sizes, int n_in,
                              void* d_out, int out_size, void* d_ws, size_t ws_size,
                              hipStream_t stream) {
    const float* normals = (const float*)d_in[0];
    // d_in[1] (weights) is mathematically unused by the reference.
    float* out = (float*)d_out;
    normals_fused_kernel<<<BATCH, NPTS, 0, stream>>>(normals, out);
}

// Round 2
// 129.298 us; speedup vs baseline: 1.1477x; 1.1477x over previous
//
#include <hip/hip_runtime.h>
#include <math.h>

#define BATCH 512
#define NPTS  512

// w(d) = exp(-acos(clamp(d,-1,1)))
// acos via A&S 4.4.46: acos(x) = sqrt(1-x) * P7(x) for x in [0,1], |err| ~ 2e-8 rad;
// negative x via acos(x) = pi - acos(-x). Branchless (cndmask).
__device__ __forceinline__ float pair_w(float d) {
    d = fminf(fmaxf(d, -1.f), 1.f);          // v_med3
    float a  = fabsf(d);                     // input modifier (free)
    float t  = 1.f - a;
    float sq = __builtin_amdgcn_sqrtf(t);    // raw v_sqrt_f32 (t in [0,1], safe)
    float p  = fmaf(-0.0012624911f, a, 0.0066700901f);
    p = fmaf(p, a, -0.0170881256f);
    p = fmaf(p, a,  0.0308918810f);
    p = fmaf(p, a, -0.0501743046f);
    p = fmaf(p, a,  0.0889789874f);
    p = fmaf(p, a, -0.2145988016f);
    p = fmaf(p, a,  1.5707963050f);
    float u  = sq * p;                                        // acos(|d|)
    float th = (d < 0.f) ? (3.14159265358979f - u) : u;       // acos(d)
    return __expf(-th);                       // v_mul(-log2e) + v_exp_f32
}

__global__ __launch_bounds__(NPTS) void normals_fused_kernel(
    const float* __restrict__ normals, float* __restrict__ out)
{
    __shared__ float4 sn[NPTS];              // packed xyz_, one ds_read_b128/iter
    const int b   = blockIdx.x;
    const int tid = threadIdx.x;
    const float* base = normals + (size_t)b * NPTS * 3;

    // Coalesced AoS load -> packed float4 in LDS (one-time).
    float* snf = (float*)sn;
    for (int k = tid; k < NPTS * 3; k += NPTS) {
        float v = base[k];
        int row = k / 3, c = k - row * 3;
        snf[row * 4 + c] = v;
    }
    __syncthreads();

    const int    i  = tid;
    const float4 ni = sn[i];
    const float  xi = ni.x, yi = ni.y, zi = ni.z;

    // Row sum over all j (diagonal included, subtracted after).
    float s = 0.f;
    #pragma unroll 8
    for (int j = 0; j < NPTS; ++j) {
        float4 nj = sn[j];                   // uniform addr -> LDS broadcast
        float d = fmaf(xi, nj.x, fmaf(yi, nj.y, zi * nj.z));
        s += pair_w(d);
    }
    s -= pair_w(fmaf(xi, xi, fmaf(yi, yi, zi * zi)));  // remove j == i

    // Global-max division skipped: uniform positive scale cancels under
    // the final normalization (verified R0: absmax 0.0).
    float ax = s * xi, ay = s * yi, az = s * zi;

    for (int off = 32; off > 0; off >>= 1) {
        ax += __shfl_down(ax, off, 64);
        ay += __shfl_down(ay, off, 64);
        az += __shfl_down(az, off, 64);
    }

    __shared__ float rx[8], ry[8], rz[8];
    const int wave = tid >> 6, lane = tid & 63;
    if (lane == 0) { rx[wave] = ax; ry[wave] = ay; rz[wave] = az; }
    __syncthreads();

    if (tid == 0) {
        float nx = 0.f, ny = 0.f, nz = 0.f;
        #pragma unroll
        for (int w = 0; w < 8; ++w) { nx += rx[w]; ny += ry[w]; nz += rz[w]; }
        float len2 = fmaf(nx, nx, fmaf(ny, ny, nz * nz));
        float inv  = rsqrtf(fmaxf(len2, 1e-20f));
        out[b * 3 + 0] = nx * inv;
        out[b * 3 + 1] = ny * inv;
        out[b * 3 + 2] = nz * inv;
    }
}

extern "C" void kernel_launch(void* const* d_in, const int* in_sizes, int n_in,
                              void* d_out, int out_size, void* d_ws, size_t ws_size,
                              hipStream_t stream) {
    const float* normals = (const float*)d_in[0];
    // d_in[1] (weights) is mathematically unused by the reference.
    float* out = (float*)d_out;
    normals_fused_kernel<<<BATCH, NPTS, 0, stream>>>(normals, out);
}